// Round 1
// 558.683 us; speedup vs baseline: 1.3367x; 1.3367x over previous
//
#include <hip/hip_runtime.h>
#include <math.h>

#define I_DIM 384
#define C_DIM 128
#define H_NUM 4
#define HD_DIM 32
#define M_DIM (I_DIM*I_DIM)       // 147456
#define INF_F 1000000000.0f
#define EPS_F 1e-5f
#define QSCALE 0.17677669529663687f   // 1/sqrt(32)

typedef __attribute__((ext_vector_type(8))) short short8;
typedef __attribute__((ext_vector_type(4))) float f32x4;
union U4S8 { uint4 u; short8 s; };

__device__ __forceinline__ unsigned short f2bf(float f) {
    unsigned int u = __float_as_uint(f);
    u += 0x7fffu + ((u >> 16) & 1u);          // round-to-nearest-even
    return (unsigned short)(u >> 16);
}
__device__ __forceinline__ float bf2f(unsigned short h) {
    return __uint_as_float((unsigned int)h << 16);
}
__device__ __forceinline__ unsigned int pk2(float a, float b) {
    return (unsigned int)f2bf(a) | ((unsigned int)f2bf(b) << 16);
}

// ---------------------------------------------------------------------------
// Pre-formatted split weights, MFMA-B-fragment-linear:
//   wfmt_dev[mat(5)][s(2)][nt(8)][ks(4)][lane(64)] : uint4 (8 bf16, k-consec)
//   element (k,n): lane = ((k>>3)&3)*16 + (n&15), nt = n>>4, ks = k>>5, j=k&7
//   mats: 0=wq (pre-scaled by QSCALE), 1=wk, 2=wg, 3=wv, 4=wo
//   s=0: bf16(w); s=1: bf16(w - bf16(w))   (hi/lo split, ~fp32 when summed)
// ---------------------------------------------------------------------------
__device__ uint4 wfmt_dev[5*4096];     // 320 KB static device memory

__device__ __forceinline__ void load_lds16(const uint4* gp, void* lp) {
    __builtin_amdgcn_global_load_lds(
        (const __attribute__((address_space(1))) unsigned int*)gp,
        (__attribute__((address_space(3))) unsigned int*)lp,
        16, 0, 0);
}

__global__ __launch_bounds__(256) void wprep_kernel(
    const float* __restrict__ wq, const float* __restrict__ wk,
    const float* __restrict__ wg, const float* __restrict__ wv,
    const float* __restrict__ wo)
{
    const int tid  = blockIdx.x*256 + threadIdx.x;   // 80 blocks -> 320 tiles
    const int l    = tid & 63, tile = tid >> 6;
    const int ks   = tile & 3, nt = (tile >> 2) & 7;
    const int s    = (tile >> 5) & 1, m = tile >> 6;
    const float* W = (m==0)?wq:(m==1)?wk:(m==2)?wg:(m==3)?wv:wo;
    const float scale = (m==0) ? QSCALE : 1.f;
    const int n  = nt*16 + (l & 15);
    const int kb = ks*32 + (l >> 4)*8;
    unsigned int hw[4];
    #pragma unroll
    for (int jp = 0; jp < 4; ++jp) {
        unsigned short hs[2];
        #pragma unroll
        for (int e = 0; e < 2; ++e) {
            float v = W[(size_t)(kb + jp*2 + e)*C_DIM + n] * scale;
            unsigned short h = f2bf(v);
            if (s) h = f2bf(v - bf2f(h));
            hs[e] = h;
        }
        hw[jp] = (unsigned int)hs[0] | ((unsigned int)hs[1] << 16);
    }
    wfmt_dev[(size_t)m*4096 + (size_t)((s*8 + nt)*4 + ks)*64 + l] =
        make_uint4(hw[0], hw[1], hw[2], hw[3]);
}

// ---------------------------------------------------------------------------
// Kernel 1: LayerNorm + z head + q/k/v/g projections via split-bf16 MFMA.
// 64 rows/block, 256 threads (4 waves x 16 rows).
// x_ln hi/lo in XOR-swizzled LDS -> A-frags preloaded to registers.
// Weights staged half-matrix (32KB) at a time via global_load_lds (frag-linear
// -> conflict-free ds_read_b128). acc = xh*wh + xl*wh + xh*wl  (~fp32).
// Outputs byte-identical to previous version: q fp32 (scaled), k bf16,
// v bf16 transposed [(i*128+c)*192 + j/2] uint pairs, g fp32, z fp32.
// ---------------------------------------------------------------------------
__global__ __launch_bounds__(256) void ln_proj_kernel(
    const float* __restrict__ x,
    const float* __restrict__ lnw, const float* __restrict__ lnb,
    const float* __restrict__ wz,  const float* __restrict__ bz,
    const float* __restrict__ bg,
    float* __restrict__ qo, unsigned short* __restrict__ ko16,
    unsigned int* __restrict__ vto, float* __restrict__ go,
    float* __restrict__ zo)
{
    __shared__ __align__(16) unsigned int xs[2*4096];  // hi|lo bf16 pairs, 32KB
    __shared__ __align__(16) uint4 wbuf4[2048];        // half-mat hi+lo, 32KB
    unsigned int* vts = xs;            // xs reused for V-transpose after preload

    const int t    = threadIdx.x;
    const int row0 = blockIdx.x * 64;

    // ---- Phase A: LayerNorm + z head + hi/lo split into swizzled LDS ----
    {
        const int r = t >> 2, qt = t & 3, c0 = qt * 32;
        const float* xrow = x + (size_t)(row0 + r)*C_DIM + c0;
        float4 xv[8];
        float s = 0.f, ss = 0.f;
        #pragma unroll
        for (int i2 = 0; i2 < 8; i2++) {
            xv[i2] = ((const float4*)xrow)[i2];
            s  += xv[i2].x + xv[i2].y + xv[i2].z + xv[i2].w;
            ss += xv[i2].x*xv[i2].x + xv[i2].y*xv[i2].y
                + xv[i2].z*xv[i2].z + xv[i2].w*xv[i2].w;
        }
        s  += __shfl_xor(s, 1);  s  += __shfl_xor(s, 2);
        ss += __shfl_xor(ss, 1); ss += __shfl_xor(ss, 2);
        const float mean = s * (1.f/128.f);
        const float var  = ss * (1.f/128.f) - mean*mean;
        const float rstd = rsqrtf(var + EPS_F);
        const int sw = (r & 7) << 2;                  // word-index XOR swizzle
        const float4* wz4 = (const float4*)wz;        // wz[c][0..3]
        float4 zacc = make_float4(0.f,0.f,0.f,0.f);
        #pragma unroll
        for (int i2 = 0; i2 < 8; i2++) {
            float4 w4 = ((const float4*)(lnw + c0))[i2];
            float4 b4 = ((const float4*)(lnb + c0))[i2];
            float4 r4;
            r4.x = (xv[i2].x - mean)*rstd*w4.x + b4.x;
            r4.y = (xv[i2].y - mean)*rstd*w4.y + b4.y;
            r4.z = (xv[i2].z - mean)*rstd*w4.z + b4.z;
            r4.w = (xv[i2].w - mean)*rstd*w4.w + b4.w;
            // z partials (stays fully fp32)
            const float4 za = wz4[c0 + i2*4 + 0];
            const float4 zb_ = wz4[c0 + i2*4 + 1];
            const float4 zc = wz4[c0 + i2*4 + 2];
            const float4 zd = wz4[c0 + i2*4 + 3];
            zacc.x += r4.x*za.x + r4.y*zb_.x + r4.z*zc.x + r4.w*zd.x;
            zacc.y += r4.x*za.y + r4.y*zb_.y + r4.z*zc.y + r4.w*zd.y;
            zacc.z += r4.x*za.z + r4.y*zb_.z + r4.z*zc.z + r4.w*zd.z;
            zacc.w += r4.x*za.w + r4.y*zb_.w + r4.z*zc.w + r4.w*zd.w;
            // hi/lo split -> LDS
            const unsigned short h0 = f2bf(r4.x), h1 = f2bf(r4.y),
                                 h2 = f2bf(r4.z), h3 = f2bf(r4.w);
            const int wi = r*64 + qt*16 + i2*2;
            xs[(wi  ) ^ sw] = (unsigned int)h0 | ((unsigned int)h1 << 16);
            xs[(wi+1) ^ sw] = (unsigned int)h2 | ((unsigned int)h3 << 16);
            const float l0 = r4.x - bf2f(h0), l1 = r4.y - bf2f(h1);
            const float l2 = r4.z - bf2f(h2), l3 = r4.w - bf2f(h3);
            xs[4096 + ((wi  ) ^ sw)] =
                (unsigned int)f2bf(l0) | ((unsigned int)f2bf(l1) << 16);
            xs[4096 + ((wi+1) ^ sw)] =
                (unsigned int)f2bf(l2) | ((unsigned int)f2bf(l3) << 16);
        }
        zacc.x += __shfl_xor(zacc.x, 1); zacc.x += __shfl_xor(zacc.x, 2);
        zacc.y += __shfl_xor(zacc.y, 1); zacc.y += __shfl_xor(zacc.y, 2);
        zacc.z += __shfl_xor(zacc.z, 1); zacc.z += __shfl_xor(zacc.z, 2);
        zacc.w += __shfl_xor(zacc.w, 1); zacc.w += __shfl_xor(zacc.w, 2);
        const float zv = (qt==0)?zacc.x:(qt==1)?zacc.y:(qt==2)?zacc.z:zacc.w;
        zo[(size_t)qt*M_DIM + row0 + r] = zv + bz[qt];
    }
    __syncthreads();

    // ---- A-frag preload: wave w owns rows w*16..+15; xs free afterwards ----
    const int w = t >> 6, l = t & 63, n16 = l & 15, quad = l >> 4;
    U4S8 ah[4], al[4];
    {
        const int arow = w*16 + n16;
        const char* xb = (const char*)xs;
        #pragma unroll
        for (int ks = 0; ks < 4; ++ks) {
            const int bofs = arow*256 + ((ks*64 + quad*16) ^ ((arow & 7) << 4));
            ah[ks].u = *(const uint4*)(xb + bofs);
            al[ks].u = *(const uint4*)(xb + 16384 + bofs);
        }
    }

    const int i_blk = row0 / I_DIM;
    const int jp0   = (row0 % I_DIM) >> 1;

    // ---- 4 projections, order q,k,g,v (v last so xs can host transpose) ----
    #pragma unroll
    for (int mi = 0; mi < 4; ++mi) {
        #pragma unroll
        for (int half = 0; half < 2; ++half) {
            __syncthreads();               // wbuf free (prev MFMA/dump done)
            #pragma unroll
            for (int it = 0; it < 8; ++it) {   // stage 8 x 1KB tiles per wave
                const int hti   = w*8 + it;    // (s,ntl,ks) tile id 0..31
                const int gtile = ((hti >> 4)*32) + half*16 + (hti & 15);
                load_lds16(wfmt_dev + (size_t)mi*4096 + (size_t)gtile*64 + l,
                           (char*)wbuf4 + hti*1024);
            }
            __syncthreads();               // drains global_load_lds (vmcnt 0)

            f32x4 acc[4];
            #pragma unroll
            for (int ntl = 0; ntl < 4; ++ntl) {
                f32x4 a = {0.f, 0.f, 0.f, 0.f};
                #pragma unroll
                for (int ks = 0; ks < 4; ++ks) {
                    U4S8 bh, bl;
                    bh.u = wbuf4[(ntl*4 + ks)*64 + l];
                    bl.u = wbuf4[1024 + (ntl*4 + ks)*64 + l];
                    a = __builtin_amdgcn_mfma_f32_16x16x32_bf16(ah[ks].s, bh.s, a, 0,0,0);
                    a = __builtin_amdgcn_mfma_f32_16x16x32_bf16(al[ks].s, bh.s, a, 0,0,0);
                    a = __builtin_amdgcn_mfma_f32_16x16x32_bf16(ah[ks].s, bl.s, a, 0,0,0);
                }
                acc[ntl] = a;
            }

            // D layout: col = n16 (+ntl*16+half*64), row = quad*4 + r
            const int rw0 = row0 + w*16 + quad*4;
            const int cb  = half*64 + n16;
            if (mi == 0) {                 // q fp32 (QSCALE pre-folded)
                #pragma unroll
                for (int ntl = 0; ntl < 4; ++ntl)
                    #pragma unroll
                    for (int r = 0; r < 4; ++r)
                        qo[(size_t)(rw0 + r)*C_DIM + cb + ntl*16] = acc[ntl][r];
            } else if (mi == 1) {          // k bf16 row-major
                #pragma unroll
                for (int ntl = 0; ntl < 4; ++ntl)
                    #pragma unroll
                    for (int r = 0; r < 4; ++r)
                        ko16[(size_t)(rw0 + r)*C_DIM + cb + ntl*16] =
                            f2bf(acc[ntl][r]);
            } else if (mi == 2) {          // g sigmoid fp32
                #pragma unroll
                for (int ntl = 0; ntl < 4; ++ntl) {
                    const float bgv = bg[cb + ntl*16];
                    #pragma unroll
                    for (int r = 0; r < 4; ++r)
                        go[(size_t)(rw0 + r)*C_DIM + cb + ntl*16] =
                            1.f/(1.f + __expf(-(acc[ntl][r] + bgv)));
                }
            } else {                       // v -> LDS transpose -> global
                // rows quad*4+{2pr,2pr+1} are adjacent j's -> pack in-thread
                #pragma unroll
                for (int ntl = 0; ntl < 4; ++ntl)
                    #pragma unroll
                    for (int pr = 0; pr < 2; ++pr)
                        vts[(ntl*16 + n16)*33 + w*8 + quad*2 + pr] =
                            pk2(acc[ntl][2*pr], acc[ntl][2*pr+1]);
                __syncthreads();
                for (int idx = t; idx < 64*32; idx += 256) {
                    const int ch_l = idx >> 5, p = idx & 31;
                    vto[((size_t)i_blk*C_DIM + half*64 + ch_l)*192 + jp0 + p] =
                        vts[ch_l*33 + p];
                }
            }
        }
    }
}

// ---------------------------------------------------------------------------
// Kernel 2: MFMA attention (UNCHANGED from previous verified version).
// ---------------------------------------------------------------------------
__global__ __launch_bounds__(256, 2) void attn_mfma_kernel(
    const float* q, const unsigned short* __restrict__ k16,
    const unsigned int* __restrict__ vt32, const float* __restrict__ zb,
    const float* __restrict__ mask, float* o)
{
    __shared__ uint4 Ks4[384*4];          // K rows bf16: 24576 B
    __shared__ uint4 VTl[32*49];          // V^T rows bf16, stride 49: 25088 B
    __shared__ unsigned int PbU[4*784];   // per-wave P chunk, stride 49: 12544 B
    __shared__ float mbl[384];            // 1536 B

    const int ii = blockIdx.x;
    const int h  = blockIdx.y;
    const int t  = threadIdx.x;
    const size_t rbase = (size_t)ii*I_DIM*C_DIM + h*HD_DIM;

    // ---- stage K (row-major head slice) and V^T ----
    for (int idx = t; idx < 1536; idx += 256) {
        const int j = idx >> 2, c4 = idx & 3;
        Ks4[j*4 + c4] = ((const uint4*)k16)[rbase/8 + (size_t)j*16 + c4];
    }
    for (int idx = t; idx < 1536; idx += 256) {
        const int d = idx / 48, m = idx - d*48;
        VTl[d*49 + m] = ((const uint4*)vt32)[((size_t)ii*C_DIM + h*HD_DIM + d)*48 + m];
    }
    for (int jj = t; jj < 384; jj += 256)
        mbl[jj] = INF_F * (mask[(size_t)ii*I_DIM + jj] - 1.f);
    __syncthreads();

    const int w = t >> 6, l = t & 63;
    const int n16 = l & 15, quad = l >> 4;

    #pragma unroll 1
    for (int qt = 0; qt < 6; qt++) {
        const int qg = w*6 + qt;          // q-tile index; rows qg*16..+15

        // ---- A-frag: Q rows fp32 -> bf16 ----
        U4S8 a;
        {
            const float* qrow = q + rbase + (size_t)(qg*16 + n16)*C_DIM + quad*8;
            const float4 f0 = ((const float4*)qrow)[0];
            const float4 f1 = ((const float4*)qrow)[1];
            a.u = make_uint4(pk2(f0.x,f0.y), pk2(f0.z,f0.w),
                             pk2(f1.x,f1.y), pk2(f1.z,f1.w));
        }

        f32x4 oacc0 = {0.f,0.f,0.f,0.f}, oacc1 = {0.f,0.f,0.f,0.f};
        float lsum[4] = {0.f, 0.f, 0.f, 0.f};
        const float* zbase = zb + (size_t)h*M_DIM
                           + (size_t)(qg*16 + quad*4)*I_DIM + n16;

        #pragma unroll 1
        for (int c = 0; c < 4; c++) {
            // z bias for this chunk (issued early; QK mfma hides latency)
            float zc[4][6];
            #pragma unroll
            for (int r = 0; r < 4; r++)
                #pragma unroll
                for (int k6 = 0; k6 < 6; k6++)
                    zc[r][k6] = zbase[(size_t)r*I_DIM + (6*c + k6)*16];
            float mbc[6];
            #pragma unroll
            for (int k6 = 0; k6 < 6; k6++)
                mbc[k6] = mbl[(6*c + k6)*16 + n16];

            // ---- QK^T: 6 mfma ----
            f32x4 accS[6];
            #pragma unroll
            for (int k6 = 0; k6 < 6; k6++) {
                U4S8 b;
                b.u = Ks4[((6*c + k6)*16 + n16)*4 + quad];
                accS[k6] = __builtin_amdgcn_mfma_f32_16x16x32_bf16(
                    a.s, b.s, (f32x4){0.f,0.f,0.f,0.f}, 0, 0, 0);
            }

            // ---- bias + exp (no max-sub) + partial row sums ----
            #pragma unroll
            for (int r = 0; r < 4; r++)
                #pragma unroll
                for (int k6 = 0; k6 < 6; k6++) {
                    const float e = __expf(accS[k6][r] + mbc[k6] + zc[r][k6]);
                    accS[k6][r] = e;
                    lsum[r] += e;
                }

            // ---- P chunk -> per-wave LDS (pair adjacent keys via shfl) ----
            #pragma unroll
            for (int k6 = 0; k6 < 6; k6++)
                #pragma unroll
                for (int r = 0; r < 4; r++) {
                    const float e  = accS[k6][r];
                    const float eo = __shfl_xor(e, 1);
                    if (!(l & 1))
                        PbU[w*784 + (quad*4+r)*49 + k6*8 + (n16 >> 1)] = pk2(e, eo);
                }

            // ---- PV: 3 km x 2 halves ----
            #pragma unroll
            for (int km = 0; km < 3; km++) {
                const int pbase = w*784 + n16*49 + quad*4 + 16*km;
                U4S8 pa;
                pa.u = make_uint4(PbU[pbase], PbU[pbase+1], PbU[pbase+2], PbU[pbase+3]);
                U4S8 vb0, vb1;
                vb0.u = VTl[(n16     )*49 + quad + 4*km + 12*c];
                vb1.u = VTl[(16 + n16)*49 + quad + 4*km + 12*c];
                oacc0 = __builtin_amdgcn_mfma_f32_16x16x32_bf16(pa.s, vb0.s, oacc0, 0,0,0);
                oacc1 = __builtin_amdgcn_mfma_f32_16x16x32_bf16(pa.s, vb1.s, oacc1, 0,0,0);
            }
        }

        // ---- normalize + store O (C-layout) ----
        #pragma unroll
        for (int r = 0; r < 4; r++) {
            float s_ = lsum[r];
            s_ += __shfl_xor(s_, 1);
            s_ += __shfl_xor(s_, 2);
            s_ += __shfl_xor(s_, 4);
            s_ += __shfl_xor(s_, 8);
            const float rcp = 1.f / s_;
            const size_t orow = rbase + (size_t)(qg*16 + quad*4 + r)*C_DIM;
            o[orow + n16]      = oacc0[r] * rcp;
            o[orow + 16 + n16] = oacc1[r] * rcp;
        }
    }
}

// ---------------------------------------------------------------------------
// Kernel 3: out = (o * g) @ wo + bo via split-bf16 MFMA (same machinery).
// g lives in d_out; final result overwrites it (per-block rows only).
// ---------------------------------------------------------------------------
__global__ __launch_bounds__(256) void out_proj_kernel(
    const float* __restrict__ o, const float* g,
    const float* __restrict__ bo, float* out)
{
    __shared__ __align__(16) unsigned int xs[2*4096];  // (o*g) hi|lo, 32KB
    __shared__ __align__(16) uint4 wbuf4[2048];        // wo half-mat, 32KB
    const int t    = threadIdx.x;
    const int row0 = blockIdx.x * 64;

    // ---- Phase A: p = o*g, hi/lo split into swizzled LDS ----
    {
        const int r = t >> 2, qt = t & 3, c0 = qt * 32;
        const float4* orow = (const float4*)(o + (size_t)(row0 + r)*C_DIM + c0);
        const float4* grow = (const float4*)(g + (size_t)(row0 + r)*C_DIM + c0);
        const int sw = (r & 7) << 2;
        #pragma unroll
        for (int i2 = 0; i2 < 8; i2++) {
            const float4 a = orow[i2];
            const float4 b = grow[i2];
            float4 p;
            p.x = a.x*b.x; p.y = a.y*b.y; p.z = a.z*b.z; p.w = a.w*b.w;
            const unsigned short h0 = f2bf(p.x), h1 = f2bf(p.y),
                                 h2 = f2bf(p.z), h3 = f2bf(p.w);
            const int wi = r*64 + qt*16 + i2*2;
            xs[(wi  ) ^ sw] = (unsigned int)h0 | ((unsigned int)h1 << 16);
            xs[(wi+1) ^ sw] = (unsigned int)h2 | ((unsigned int)h3 << 16);
            const float l0 = p.x - bf2f(h0), l1 = p.y - bf2f(h1);
            const float l2 = p.z - bf2f(h2), l3 = p.w - bf2f(h3);
            xs[4096 + ((wi  ) ^ sw)] =
                (unsigned int)f2bf(l0) | ((unsigned int)f2bf(l1) << 16);
            xs[4096 + ((wi+1) ^ sw)] =
                (unsigned int)f2bf(l2) | ((unsigned int)f2bf(l3) << 16);
        }
    }
    __syncthreads();

    const int w = t >> 6, l = t & 63, n16 = l & 15, quad = l >> 4;
    U4S8 ah[4], al[4];
    {
        const int arow = w*16 + n16;
        const char* xb = (const char*)xs;
        #pragma unroll
        for (int ks = 0; ks < 4; ++ks) {
            const int bofs = arow*256 + ((ks*64 + quad*16) ^ ((arow & 7) << 4));
            ah[ks].u = *(const uint4*)(xb + bofs);
            al[ks].u = *(const uint4*)(xb + 16384 + bofs);
        }
    }

    #pragma unroll
    for (int half = 0; half < 2; ++half) {
        __syncthreads();
        #pragma unroll
        for (int it = 0; it < 8; ++it) {
            const int hti   = w*8 + it;
            const int gtile = ((hti >> 4)*32) + half*16 + (hti & 15);
            load_lds16(wfmt_dev + (size_t)4*4096 + (size_t)gtile*64 + l,
                       (char*)wbuf4 + hti*1024);
        }
        __syncthreads();

        f32x4 acc[4];
        #pragma unroll
        for (int ntl = 0; ntl < 4; ++ntl) {
            f32x4 a = {0.f, 0.f, 0.f, 0.f};
            #pragma unroll
            for (int ks = 0; ks < 4; ++ks) {
                U4S8 bh, bl;
                bh.u = wbuf4[(ntl*4 + ks)*64 + l];
                bl.u = wbuf4[1024 + (ntl*4 + ks)*64 + l];
                a = __builtin_amdgcn_mfma_f32_16x16x32_bf16(ah[ks].s, bh.s, a, 0,0,0);
                a = __builtin_amdgcn_mfma_f32_16x16x32_bf16(al[ks].s, bh.s, a, 0,0,0);
                a = __builtin_amdgcn_mfma_f32_16x16x32_bf16(ah[ks].s, bl.s, a, 0,0,0);
            }
            acc[ntl] = a;
        }

        const int rw0 = row0 + w*16 + quad*4;
        #pragma unroll
        for (int ntl = 0; ntl < 4; ++ntl) {
            const int n = half*64 + ntl*16 + n16;
            const float bov = bo[n];
            #pragma unroll
            for (int r = 0; r < 4; ++r)
                out[(size_t)(rw0 + r)*C_DIM + n] = acc[ntl][r] + bov;
        }
    }
}

extern "C" void kernel_launch(void* const* d_in, const int* in_sizes, int n_in,
                              void* d_out, int out_size, void* d_ws, size_t ws_size,
                              hipStream_t stream)
{
    (void)in_sizes; (void)n_in; (void)out_size; (void)ws_size;
    const float* x    = (const float*)d_in[0];
    const float* mask = (const float*)d_in[1];
    const float* lnw  = (const float*)d_in[2];
    const float* lnb  = (const float*)d_in[3];
    const float* wz   = (const float*)d_in[4];
    const float* bz   = (const float*)d_in[5];
    const float* wq   = (const float*)d_in[6];
    const float* wk   = (const float*)d_in[7];
    const float* wv   = (const float*)d_in[8];
    const float* wg   = (const float*)d_in[9];
    const float* bg   = (const float*)d_in[10];
    const float* wo   = (const float*)d_in[11];
    const float* bo   = (const float*)d_in[12];

    // ws layout (153.4 MB, unchanged):
    //   qb   fp32 M*128  (q; o overwrites it in attention)
    //   zbuf fp32 4*M
    //   kb16 bf16 M*128 row-major
    //   vt32 bf16 M*128 transposed [i][c][j], packed uint pairs along j
    float* ws = (float*)d_ws;
    float* qb   = ws;
    float* zbuf = qb + (size_t)M_DIM*C_DIM;
    unsigned short* kb16 = (unsigned short*)(zbuf + (size_t)H_NUM*M_DIM);
    unsigned int*   vt32 = (unsigned int*)(kb16 + (size_t)M_DIM*C_DIM);
    float* gbuf = (float*)d_out;     // g parked in d_out, consumed by kernel 3

    wprep_kernel<<<80, 256, 0, stream>>>(wq, wk, wg, wv, wo);
    ln_proj_kernel<<<M_DIM/64, 256, 0, stream>>>(
        x, lnw, lnb, wz, bz, bg, qb, kb16, vt32, gbuf, zbuf);
    attn_mfma_kernel<<<dim3(I_DIM, H_NUM), 256, 0, stream>>>(
        qb, kb16, vt32, zbuf, mask, qb /* o over q */);
    out_proj_kernel<<<M_DIM/64, 256, 0, stream>>>(
        qb, gbuf, bo, (float*)d_out);
}

// Round 2
// 500.038 us; speedup vs baseline: 1.4935x; 1.1173x over previous
//
#include <hip/hip_runtime.h>
#include <math.h>

#define I_DIM 384
#define C_DIM 128
#define H_NUM 4
#define HD_DIM 32
#define M_DIM (I_DIM*I_DIM)       // 147456
#define INF_F 1000000000.0f
#define EPS_F 1e-5f
#define QSCALE 0.17677669529663687f   // 1/sqrt(32)

typedef __attribute__((ext_vector_type(8))) short short8;
typedef __attribute__((ext_vector_type(4))) float f32x4;
union U4S8 { uint4 u; short8 s; };

__device__ __forceinline__ unsigned short f2bf(float f) {
    unsigned int u = __float_as_uint(f);
    u += 0x7fffu + ((u >> 16) & 1u);          // round-to-nearest-even
    return (unsigned short)(u >> 16);
}
__device__ __forceinline__ float bf2f(unsigned short h) {
    return __uint_as_float((unsigned int)h << 16);
}
__device__ __forceinline__ unsigned int pk2(float a, float b) {
    return (unsigned int)f2bf(a) | ((unsigned int)f2bf(b) << 16);
}

// ---------------------------------------------------------------------------
// Pre-formatted split weights, MFMA-B-fragment-linear:
//   wfmt_dev[mat(5)][s(2)][nt(8)][ks(4)][lane(64)] : uint4 (8 bf16, k-consec)
//   element (k,n): lane = ((k>>3)&3)*16 + (n&15), nt = n>>4, ks = k>>5, j=k&7
//   mats: 0=wq (pre-scaled by QSCALE), 1=wk, 2=wg, 3=wv, 4=wo
//   s=0: bf16(w); s=1: bf16(w - bf16(w))   (hi/lo split, ~fp32 when summed)
// ---------------------------------------------------------------------------
__device__ uint4 wfmt_dev[5*4096];     // 320 KB static device memory

__device__ __forceinline__ void load_lds16(const uint4* gp, void* lp) {
    __builtin_amdgcn_global_load_lds(
        (const __attribute__((address_space(1))) unsigned int*)gp,
        (__attribute__((address_space(3))) unsigned int*)lp,
        16, 0, 0);
}

__global__ __launch_bounds__(256) void wprep_kernel(
    const float* __restrict__ wq, const float* __restrict__ wk,
    const float* __restrict__ wg, const float* __restrict__ wv,
    const float* __restrict__ wo)
{
    const int tid  = blockIdx.x*256 + threadIdx.x;   // 80 blocks -> 320 tiles
    const int l    = tid & 63, tile = tid >> 6;
    const int ks   = tile & 3, nt = (tile >> 2) & 7;
    const int s    = (tile >> 5) & 1, m = tile >> 6;
    const float* W = (m==0)?wq:(m==1)?wk:(m==2)?wg:(m==3)?wv:wo;
    const float scale = (m==0) ? QSCALE : 1.f;
    const int n  = nt*16 + (l & 15);
    const int kb = ks*32 + (l >> 4)*8;
    unsigned int hw[4];
    #pragma unroll
    for (int jp = 0; jp < 4; ++jp) {
        unsigned short hs[2];
        #pragma unroll
        for (int e = 0; e < 2; ++e) {
            float v = W[(size_t)(kb + jp*2 + e)*C_DIM + n] * scale;
            unsigned short h = f2bf(v);
            if (s) h = f2bf(v - bf2f(h));
            hs[e] = h;
        }
        hw[jp] = (unsigned int)hs[0] | ((unsigned int)hs[1] << 16);
    }
    wfmt_dev[(size_t)m*4096 + (size_t)((s*8 + nt)*4 + ks)*64 + l] =
        make_uint4(hw[0], hw[1], hw[2], hw[3]);
}

// ---------------------------------------------------------------------------
// Kernel 1: LayerNorm + z head + q/k/v/g projections via split-bf16 MFMA.
// Occupancy-optimized: LDS 32KB (xs 16KB two-pass + wbuf 16KB quarter),
// __launch_bounds__(256,4) -> VGPR<=128 -> 4 blocks/CU (16 waves).
// 16 quarter-rounds; round r+1 staged right after round-r read barrier;
// round 0 prefetched at kernel entry (hidden under LayerNorm phase).
// Accumulation order identical to previous version -> bit-identical outputs.
// ---------------------------------------------------------------------------
__global__ __launch_bounds__(256, 4) void ln_proj_kernel(
    const float* __restrict__ x,
    const float* __restrict__ lnw, const float* __restrict__ lnb,
    const float* __restrict__ wz,  const float* __restrict__ bz,
    const float* __restrict__ bg,
    float* __restrict__ qo, unsigned short* __restrict__ ko16,
    unsigned int* __restrict__ vto, float* __restrict__ go,
    float* __restrict__ zo)
{
    __shared__ __align__(16) unsigned int xs[4096];   // 16KB: hi, then lo, then vts
    __shared__ __align__(16) uint4 wbuf4[1024];       // 16KB quarter (hi+lo, 2 nt)
    unsigned int* vts = xs;

    const int t    = threadIdx.x;
    const int row0 = blockIdx.x * 64;
    const int w = t >> 6, l = t & 63, n16 = l & 15, quad = l >> 4;

    // ---- prefetch round 0 (wq, quarter 0): 16 tiles, 4 per wave ----
    #pragma unroll
    for (int it = 0; it < 4; ++it) {
        const int tl = w*4 + it;                  // s=tl>>3, ntl=(tl>>2)&1, ks=tl&3
        const int s = tl >> 3, ntl = (tl >> 2) & 1, ks = tl & 3;
        load_lds16(wfmt_dev + (size_t)((s*8 + ntl)*4 + ks)*64 + l,
                   (char*)wbuf4 + tl*1024);
    }

    // ---- Phase A: LayerNorm + z head; LN results kept in registers ----
    float4 xv[8];                 // raw x, then overwritten with x_ln (fp32)
    const int r = t >> 2, qt = t & 3, c0 = qt * 32;
    const int sw = (r & 7) << 2;  // word-index XOR swizzle
    {
        const float* xrow = x + (size_t)(row0 + r)*C_DIM + c0;
        float s = 0.f, ss = 0.f;
        #pragma unroll
        for (int i2 = 0; i2 < 8; i2++) {
            xv[i2] = ((const float4*)xrow)[i2];
            s  += xv[i2].x + xv[i2].y + xv[i2].z + xv[i2].w;
            ss += xv[i2].x*xv[i2].x + xv[i2].y*xv[i2].y
                + xv[i2].z*xv[i2].z + xv[i2].w*xv[i2].w;
        }
        s  += __shfl_xor(s, 1);  s  += __shfl_xor(s, 2);
        ss += __shfl_xor(ss, 1); ss += __shfl_xor(ss, 2);
        const float mean = s * (1.f/128.f);
        const float var  = ss * (1.f/128.f) - mean*mean;
        const float rstd = rsqrtf(var + EPS_F);
        const float4* wz4 = (const float4*)wz;        // wz[c][0..3]
        float4 zacc = make_float4(0.f,0.f,0.f,0.f);
        #pragma unroll
        for (int i2 = 0; i2 < 8; i2++) {
            float4 w4 = ((const float4*)(lnw + c0))[i2];
            float4 b4 = ((const float4*)(lnb + c0))[i2];
            float4 r4;
            r4.x = (xv[i2].x - mean)*rstd*w4.x + b4.x;
            r4.y = (xv[i2].y - mean)*rstd*w4.y + b4.y;
            r4.z = (xv[i2].z - mean)*rstd*w4.z + b4.z;
            r4.w = (xv[i2].w - mean)*rstd*w4.w + b4.w;
            // z partials (fully fp32)
            const float4 za = wz4[c0 + i2*4 + 0];
            const float4 zb_ = wz4[c0 + i2*4 + 1];
            const float4 zc = wz4[c0 + i2*4 + 2];
            const float4 zd = wz4[c0 + i2*4 + 3];
            zacc.x += r4.x*za.x + r4.y*zb_.x + r4.z*zc.x + r4.w*zd.x;
            zacc.y += r4.x*za.y + r4.y*zb_.y + r4.z*zc.y + r4.w*zd.y;
            zacc.z += r4.x*za.z + r4.y*zb_.z + r4.z*zc.z + r4.w*zd.z;
            zacc.w += r4.x*za.w + r4.y*zb_.w + r4.z*zc.w + r4.w*zd.w;
            // hi -> LDS (pass 1)
            const int wi = r*64 + qt*16 + i2*2;
            xs[(wi  ) ^ sw] = pk2(r4.x, r4.y);
            xs[(wi+1) ^ sw] = pk2(r4.z, r4.w);
            xv[i2] = r4;                          // keep x_ln for pass 2
        }
        zacc.x += __shfl_xor(zacc.x, 1); zacc.x += __shfl_xor(zacc.x, 2);
        zacc.y += __shfl_xor(zacc.y, 1); zacc.y += __shfl_xor(zacc.y, 2);
        zacc.z += __shfl_xor(zacc.z, 1); zacc.z += __shfl_xor(zacc.z, 2);
        zacc.w += __shfl_xor(zacc.w, 1); zacc.w += __shfl_xor(zacc.w, 2);
        const float zv = (qt==0)?zacc.x:(qt==1)?zacc.y:(qt==2)?zacc.z:zacc.w;
        zo[(size_t)qt*M_DIM + row0 + r] = zv + bz[qt];
    }
    __syncthreads();              // hi complete (also drains round-0 prefetch)

    // ---- A-frag preload, pass 1: hi ----
    U4S8 ah[4], al[4];
    const int arow = w*16 + n16;
    #pragma unroll
    for (int ks = 0; ks < 4; ++ks) {
        const int bofs = arow*256 + ((ks*64 + quad*16) ^ ((arow & 7) << 4));
        ah[ks].u = *(const uint4*)((const char*)xs + bofs);
    }
    __syncthreads();

    // ---- pass 2: lo = x_ln - bf16(x_ln) ----
    #pragma unroll
    for (int i2 = 0; i2 < 8; i2++) {
        const float4 r4 = xv[i2];
        const unsigned short h0 = f2bf(r4.x), h1 = f2bf(r4.y),
                             h2 = f2bf(r4.z), h3 = f2bf(r4.w);
        const int wi = r*64 + qt*16 + i2*2;
        xs[(wi  ) ^ sw] = (unsigned int)f2bf(r4.x - bf2f(h0))
                        | ((unsigned int)f2bf(r4.y - bf2f(h1)) << 16);
        xs[(wi+1) ^ sw] = (unsigned int)f2bf(r4.z - bf2f(h2))
                        | ((unsigned int)f2bf(r4.w - bf2f(h3)) << 16);
    }
    __syncthreads();
    #pragma unroll
    for (int ks = 0; ks < 4; ++ks) {
        const int bofs = arow*256 + ((ks*64 + quad*16) ^ ((arow & 7) << 4));
        al[ks].u = *(const uint4*)((const char*)xs + bofs);
    }
    // no barrier needed: round-0 wbuf already drained; xs (vts) reused only
    // in mi==3 rounds, which are behind multiple barriers.

    const int i_blk = row0 / I_DIM;
    const int jp0   = (row0 % I_DIM) >> 1;
    const int rw0   = row0 + w*16 + quad*4;

    // ---- 16 quarter-rounds: (mat q,k,g,v) x (4 col-quarters) ----
    #pragma unroll
    for (int rd = 0; rd < 16; ++rd) {
        const int mi = rd >> 2, qq = rd & 3;

        f32x4 acc[2];
        #pragma unroll
        for (int ntl = 0; ntl < 2; ++ntl) {
            f32x4 a = {0.f, 0.f, 0.f, 0.f};
            #pragma unroll
            for (int ks = 0; ks < 4; ++ks) {
                U4S8 bh, bl;
                bh.u = wbuf4[(    ntl*4 + ks)*64 + l];
                bl.u = wbuf4[(8 + ntl*4 + ks)*64 + l];
                a = __builtin_amdgcn_mfma_f32_16x16x32_bf16(ah[ks].s, bh.s, a, 0,0,0);
                a = __builtin_amdgcn_mfma_f32_16x16x32_bf16(al[ks].s, bh.s, a, 0,0,0);
                a = __builtin_amdgcn_mfma_f32_16x16x32_bf16(ah[ks].s, bl.s, a, 0,0,0);
            }
            acc[ntl] = a;
        }

        // ---- epilogue (cols qq*32 + ntl*16 + n16; rows rw0+rr) ----
        if (mi == 0) {                 // q fp32 (QSCALE pre-folded)
            #pragma unroll
            for (int ntl = 0; ntl < 2; ++ntl)
                #pragma unroll
                for (int rr = 0; rr < 4; ++rr)
                    qo[(size_t)(rw0 + rr)*C_DIM + qq*32 + ntl*16 + n16] =
                        acc[ntl][rr];
        } else if (mi == 1) {          // k bf16 row-major
            #pragma unroll
            for (int ntl = 0; ntl < 2; ++ntl)
                #pragma unroll
                for (int rr = 0; rr < 4; ++rr)
                    ko16[(size_t)(rw0 + rr)*C_DIM + qq*32 + ntl*16 + n16] =
                        f2bf(acc[ntl][rr]);
        } else if (mi == 2) {          // g sigmoid fp32
            #pragma unroll
            for (int ntl = 0; ntl < 2; ++ntl) {
                const float bgv = bg[qq*32 + ntl*16 + n16];
                #pragma unroll
                for (int rr = 0; rr < 4; ++rr)
                    go[(size_t)(rw0 + rr)*C_DIM + qq*32 + ntl*16 + n16] =
                        1.f/(1.f + __expf(-(acc[ntl][rr] + bgv)));
            }
        } else {                       // v -> LDS transpose -> global
            #pragma unroll
            for (int ntl = 0; ntl < 2; ++ntl)
                #pragma unroll
                for (int pr = 0; pr < 2; ++pr)
                    vts[(ntl*16 + n16)*33 + w*8 + quad*2 + pr] =
                        pk2(acc[ntl][2*pr], acc[ntl][2*pr+1]);
            __syncthreads();
            for (int idx = t; idx < 32*32; idx += 256) {
                const int ch_l = idx >> 5, p = idx & 31;
                vto[((size_t)i_blk*C_DIM + qq*32 + ch_l)*192 + jp0 + p] =
                    vts[ch_l*33 + p];
            }
        }

        __syncthreads();               // all waves done reading wbuf (and vts)
        if (rd < 15) {                 // stage next quarter
            const int m2 = (rd+1) >> 2, q2 = (rd+1) & 3;
            #pragma unroll
            for (int it = 0; it < 4; ++it) {
                const int tl = w*4 + it;
                const int s = tl >> 3, ntl2 = (tl >> 2) & 1, ks = tl & 3;
                load_lds16(wfmt_dev + (size_t)m2*4096
                           + (size_t)((s*8 + (q2*2 + ntl2))*4 + ks)*64 + l,
                           (char*)wbuf4 + tl*1024);
            }
        }
        __syncthreads();               // drains stage (vmcnt 0 in syncthreads)
    }
}

// ---------------------------------------------------------------------------
// Kernel 2: MFMA attention (UNCHANGED from previous verified version).
// ---------------------------------------------------------------------------
__global__ __launch_bounds__(256, 2) void attn_mfma_kernel(
    const float* q, const unsigned short* __restrict__ k16,
    const unsigned int* __restrict__ vt32, const float* __restrict__ zb,
    const float* __restrict__ mask, float* o)
{
    __shared__ uint4 Ks4[384*4];          // K rows bf16: 24576 B
    __shared__ uint4 VTl[32*49];          // V^T rows bf16, stride 49: 25088 B
    __shared__ unsigned int PbU[4*784];   // per-wave P chunk, stride 49: 12544 B
    __shared__ float mbl[384];            // 1536 B

    const int ii = blockIdx.x;
    const int h  = blockIdx.y;
    const int t  = threadIdx.x;
    const size_t rbase = (size_t)ii*I_DIM*C_DIM + h*HD_DIM;

    // ---- stage K (row-major head slice) and V^T ----
    for (int idx = t; idx < 1536; idx += 256) {
        const int j = idx >> 2, c4 = idx & 3;
        Ks4[j*4 + c4] = ((const uint4*)k16)[rbase/8 + (size_t)j*16 + c4];
    }
    for (int idx = t; idx < 1536; idx += 256) {
        const int d = idx / 48, m = idx - d*48;
        VTl[d*49 + m] = ((const uint4*)vt32)[((size_t)ii*C_DIM + h*HD_DIM + d)*48 + m];
    }
    for (int jj = t; jj < 384; jj += 256)
        mbl[jj] = INF_F * (mask[(size_t)ii*I_DIM + jj] - 1.f);
    __syncthreads();

    const int w = t >> 6, l = t & 63;
    const int n16 = l & 15, quad = l >> 4;

    #pragma unroll 1
    for (int qt = 0; qt < 6; qt++) {
        const int qg = w*6 + qt;          // q-tile index; rows qg*16..+15

        // ---- A-frag: Q rows fp32 -> bf16 ----
        U4S8 a;
        {
            const float* qrow = q + rbase + (size_t)(qg*16 + n16)*C_DIM + quad*8;
            const float4 f0 = ((const float4*)qrow)[0];
            const float4 f1 = ((const float4*)qrow)[1];
            a.u = make_uint4(pk2(f0.x,f0.y), pk2(f0.z,f0.w),
                             pk2(f1.x,f1.y), pk2(f1.z,f1.w));
        }

        f32x4 oacc0 = {0.f,0.f,0.f,0.f}, oacc1 = {0.f,0.f,0.f,0.f};
        float lsum[4] = {0.f, 0.f, 0.f, 0.f};
        const float* zbase = zb + (size_t)h*M_DIM
                           + (size_t)(qg*16 + quad*4)*I_DIM + n16;

        #pragma unroll 1
        for (int c = 0; c < 4; c++) {
            // z bias for this chunk (issued early; QK mfma hides latency)
            float zc[4][6];
            #pragma unroll
            for (int r = 0; r < 4; r++)
                #pragma unroll
                for (int k6 = 0; k6 < 6; k6++)
                    zc[r][k6] = zbase[(size_t)r*I_DIM + (6*c + k6)*16];
            float mbc[6];
            #pragma unroll
            for (int k6 = 0; k6 < 6; k6++)
                mbc[k6] = mbl[(6*c + k6)*16 + n16];

            // ---- QK^T: 6 mfma ----
            f32x4 accS[6];
            #pragma unroll
            for (int k6 = 0; k6 < 6; k6++) {
                U4S8 b;
                b.u = Ks4[((6*c + k6)*16 + n16)*4 + quad];
                accS[k6] = __builtin_amdgcn_mfma_f32_16x16x32_bf16(
                    a.s, b.s, (f32x4){0.f,0.f,0.f,0.f}, 0, 0, 0);
            }

            // ---- bias + exp (no max-sub) + partial row sums ----
            #pragma unroll
            for (int r = 0; r < 4; r++)
                #pragma unroll
                for (int k6 = 0; k6 < 6; k6++) {
                    const float e = __expf(accS[k6][r] + mbc[k6] + zc[r][k6]);
                    accS[k6][r] = e;
                    lsum[r] += e;
                }

            // ---- P chunk -> per-wave LDS (pair adjacent keys via shfl) ----
            #pragma unroll
            for (int k6 = 0; k6 < 6; k6++)
                #pragma unroll
                for (int r = 0; r < 4; r++) {
                    const float e  = accS[k6][r];
                    const float eo = __shfl_xor(e, 1);
                    if (!(l & 1))
                        PbU[w*784 + (quad*4+r)*49 + k6*8 + (n16 >> 1)] = pk2(e, eo);
                }

            // ---- PV: 3 km x 2 halves ----
            #pragma unroll
            for (int km = 0; km < 3; km++) {
                const int pbase = w*784 + n16*49 + quad*4 + 16*km;
                U4S8 pa;
                pa.u = make_uint4(PbU[pbase], PbU[pbase+1], PbU[pbase+2], PbU[pbase+3]);
                U4S8 vb0, vb1;
                vb0.u = VTl[(n16     )*49 + quad + 4*km + 12*c];
                vb1.u = VTl[(16 + n16)*49 + quad + 4*km + 12*c];
                oacc0 = __builtin_amdgcn_mfma_f32_16x16x32_bf16(pa.s, vb0.s, oacc0, 0,0,0);
                oacc1 = __builtin_amdgcn_mfma_f32_16x16x32_bf16(pa.s, vb1.s, oacc1, 0,0,0);
            }
        }

        // ---- normalize + store O (C-layout) ----
        #pragma unroll
        for (int r = 0; r < 4; r++) {
            float s_ = lsum[r];
            s_ += __shfl_xor(s_, 1);
            s_ += __shfl_xor(s_, 2);
            s_ += __shfl_xor(s_, 4);
            s_ += __shfl_xor(s_, 8);
            const float rcp = 1.f / s_;
            const size_t orow = rbase + (size_t)(qg*16 + quad*4 + r)*C_DIM;
            o[orow + n16]      = oacc0[r] * rcp;
            o[orow + 16 + n16] = oacc1[r] * rcp;
        }
    }
}

// ---------------------------------------------------------------------------
// Kernel 3: out = (o * g) @ wo + bo, same occupancy-optimized structure.
// LDS 32KB, launch_bounds(256,4) -> 4 blocks/CU. wo quarter 0 prefetched
// at entry (hidden under the o*g phase).
// ---------------------------------------------------------------------------
__global__ __launch_bounds__(256, 4) void out_proj_kernel(
    const float* __restrict__ o, const float* g,
    const float* __restrict__ bo, float* out)
{
    __shared__ __align__(16) unsigned int xs[4096];   // 16KB two-pass
    __shared__ __align__(16) uint4 wbuf4[1024];       // 16KB quarter
    const int t    = threadIdx.x;
    const int row0 = blockIdx.x * 64;
    const int w = t >> 6, l = t & 63, n16 = l & 15, quad = l >> 4;

    // ---- prefetch wo quarter 0 ----
    #pragma unroll
    for (int it = 0; it < 4; ++it) {
        const int tl = w*4 + it;
        const int s = tl >> 3, ntl = (tl >> 2) & 1, ks = tl & 3;
        load_lds16(wfmt_dev + (size_t)4*4096 + (size_t)((s*8 + ntl)*4 + ks)*64 + l,
                   (char*)wbuf4 + tl*1024);
    }

    // ---- Phase A: p = o*g (kept in regs), hi -> LDS ----
    float4 pv[8];
    const int r = t >> 2, qt = t & 3, c0 = qt * 32;
    const int sw = (r & 7) << 2;
    {
        const float4* orow = (const float4*)(o + (size_t)(row0 + r)*C_DIM + c0);
        const float4* grow = (const float4*)(g + (size_t)(row0 + r)*C_DIM + c0);
        #pragma unroll
        for (int i2 = 0; i2 < 8; i2++) {
            const float4 a = orow[i2];
            const float4 b = grow[i2];
            float4 p;
            p.x = a.x*b.x; p.y = a.y*b.y; p.z = a.z*b.z; p.w = a.w*b.w;
            const int wi = r*64 + qt*16 + i2*2;
            xs[(wi  ) ^ sw] = pk2(p.x, p.y);
            xs[(wi+1) ^ sw] = pk2(p.z, p.w);
            pv[i2] = p;
        }
    }
    __syncthreads();               // hi done (also drains quarter-0 prefetch)

    U4S8 ah[4], al[4];
    const int arow = w*16 + n16;
    #pragma unroll
    for (int ks = 0; ks < 4; ++ks) {
        const int bofs = arow*256 + ((ks*64 + quad*16) ^ ((arow & 7) << 4));
        ah[ks].u = *(const uint4*)((const char*)xs + bofs);
    }
    __syncthreads();
    #pragma unroll
    for (int i2 = 0; i2 < 8; i2++) {
        const float4 p = pv[i2];
        const unsigned short h0 = f2bf(p.x), h1 = f2bf(p.y),
                             h2 = f2bf(p.z), h3 = f2bf(p.w);
        const int wi = r*64 + qt*16 + i2*2;
        xs[(wi  ) ^ sw] = (unsigned int)f2bf(p.x - bf2f(h0))
                        | ((unsigned int)f2bf(p.y - bf2f(h1)) << 16);
        xs[(wi+1) ^ sw] = (unsigned int)f2bf(p.z - bf2f(h2))
                        | ((unsigned int)f2bf(p.w - bf2f(h3)) << 16);
    }
    __syncthreads();
    #pragma unroll
    for (int ks = 0; ks < 4; ++ks) {
        const int bofs = arow*256 + ((ks*64 + quad*16) ^ ((arow & 7) << 4));
        al[ks].u = *(const uint4*)((const char*)xs + bofs);
    }

    const int rw0 = row0 + w*16 + quad*4;
    #pragma unroll
    for (int qq = 0; qq < 4; ++qq) {
        f32x4 acc[2];
        #pragma unroll
        for (int ntl = 0; ntl < 2; ++ntl) {
            f32x4 a = {0.f, 0.f, 0.f, 0.f};
            #pragma unroll
            for (int ks = 0; ks < 4; ++ks) {
                U4S8 bh, bl;
                bh.u = wbuf4[(    ntl*4 + ks)*64 + l];
                bl.u = wbuf4[(8 + ntl*4 + ks)*64 + l];
                a = __builtin_amdgcn_mfma_f32_16x16x32_bf16(ah[ks].s, bh.s, a, 0,0,0);
                a = __builtin_amdgcn_mfma_f32_16x16x32_bf16(al[ks].s, bh.s, a, 0,0,0);
                a = __builtin_amdgcn_mfma_f32_16x16x32_bf16(ah[ks].s, bl.s, a, 0,0,0);
            }
            acc[ntl] = a;
        }
        #pragma unroll
        for (int ntl = 0; ntl < 2; ++ntl) {
            const int n = qq*32 + ntl*16 + n16;
            const float bov = bo[n];
            #pragma unroll
            for (int rr = 0; rr < 4; ++rr)
                out[(size_t)(rw0 + rr)*C_DIM + n] = acc[ntl][rr] + bov;
        }
        __syncthreads();
        if (qq < 3) {
            const int q2 = qq + 1;
            #pragma unroll
            for (int it = 0; it < 4; ++it) {
                const int tl = w*4 + it;
                const int s = tl >> 3, ntl2 = (tl >> 2) & 1, ks = tl & 3;
                load_lds16(wfmt_dev + (size_t)4*4096
                           + (size_t)((s*8 + (q2*2 + ntl2))*4 + ks)*64 + l,
                           (char*)wbuf4 + tl*1024);
            }
        }
        __syncthreads();
    }
}

extern "C" void kernel_launch(void* const* d_in, const int* in_sizes, int n_in,
                              void* d_out, int out_size, void* d_ws, size_t ws_size,
                              hipStream_t stream)
{
    (void)in_sizes; (void)n_in; (void)out_size; (void)ws_size;
    const float* x    = (const float*)d_in[0];
    const float* mask = (const float*)d_in[1];
    const float* lnw  = (const float*)d_in[2];
    const float* lnb  = (const float*)d_in[3];
    const float* wz   = (const float*)d_in[4];
    const float* bz   = (const float*)d_in[5];
    const float* wq   = (const float*)d_in[6];
    const float* wk   = (const float*)d_in[7];
    const float* wv   = (const float*)d_in[8];
    const float* wg   = (const float*)d_in[9];
    const float* bg   = (const float*)d_in[10];
    const float* wo   = (const float*)d_in[11];
    const float* bo   = (const float*)d_in[12];

    // ws layout (153.4 MB, unchanged):
    //   qb   fp32 M*128  (q; o overwrites it in attention)
    //   zbuf fp32 4*M
    //   kb16 bf16 M*128 row-major
    //   vt32 bf16 M*128 transposed [i][c][j], packed uint pairs along j
    float* ws = (float*)d_ws;
    float* qb   = ws;
    float* zbuf = qb + (size_t)M_DIM*C_DIM;
    unsigned short* kb16 = (unsigned short*)(zbuf + (size_t)H_NUM*M_DIM);
    unsigned int*   vt32 = (unsigned int*)(kb16 + (size_t)M_DIM*C_DIM);
    float* gbuf = (float*)d_out;     // g parked in d_out, consumed by kernel 3

    wprep_kernel<<<80, 256, 0, stream>>>(wq, wk, wg, wv, wo);
    ln_proj_kernel<<<M_DIM/64, 256, 0, stream>>>(
        x, lnw, lnb, wz, bz, bg, qb, kb16, vt32, gbuf, zbuf);
    attn_mfma_kernel<<<dim3(I_DIM, H_NUM), 256, 0, stream>>>(
        qb, kb16, vt32, zbuf, mask, qb /* o over q */);
    out_proj_kernel<<<M_DIM/64, 256, 0, stream>>>(
        qb, gbuf, bo, (float*)d_out);
}

// Round 4
// 440.882 us; speedup vs baseline: 1.6939x; 1.1342x over previous
//
#include <hip/hip_runtime.h>
#include <math.h>

#define I_DIM 384
#define C_DIM 128
#define H_NUM 4
#define HD_DIM 32
#define M_DIM (I_DIM*I_DIM)       // 147456
#define INF_F 1000000000.0f
#define EPS_F 1e-5f
#define QSCALE 0.17677669529663687f   // 1/sqrt(32)

typedef __attribute__((ext_vector_type(8))) short short8;
typedef __attribute__((ext_vector_type(4))) float f32x4;
union U4S8 { uint4 u; short8 s; };

__device__ __forceinline__ unsigned short f2bf(float f) {
    unsigned int u = __float_as_uint(f);
    u += 0x7fffu + ((u >> 16) & 1u);          // round-to-nearest-even
    return (unsigned short)(u >> 16);
}
__device__ __forceinline__ float bf2f(unsigned short h) {
    return __uint_as_float((unsigned int)h << 16);
}
__device__ __forceinline__ unsigned int pk2(float a, float b) {
    return (unsigned int)f2bf(a) | ((unsigned int)f2bf(b) << 16);
}
// HW packed f32->bf16 (RNE), 1 instr instead of ~8
__device__ __forceinline__ unsigned int cvtpk(float lo, float hi) {
    unsigned int r;
    asm("v_cvt_pk_bf16_f32 %0, %1, %2" : "=v"(r) : "v"(lo), "v"(hi));
    return r;
}

// ---------------------------------------------------------------------------
// Pre-formatted split weights, MFMA-B-fragment-linear:
//   wfmt_dev[mat(5)][s(2)][nt(8)][ks(4)][lane(64)] : uint4 (8 bf16, k-consec)
//   mats: 0=wq (pre-scaled by QSCALE), 1=wk, 2=wg, 3=wv, 4=wo
//   s=0: bf16(w); s=1: bf16(w - bf16(w))   (hi/lo split, ~fp32 when summed)
// ---------------------------------------------------------------------------
__device__ uint4 wfmt_dev[5*4096];     // 320 KB static device memory

__device__ __forceinline__ void load_lds16(const uint4* gp, void* lp) {
    __builtin_amdgcn_global_load_lds(
        (const __attribute__((address_space(1))) unsigned int*)gp,
        (__attribute__((address_space(3))) unsigned int*)lp,
        16, 0, 0);
}

__global__ __launch_bounds__(256) void wprep_kernel(
    const float* __restrict__ wq, const float* __restrict__ wk,
    const float* __restrict__ wg, const float* __restrict__ wv,
    const float* __restrict__ wo)
{
    const int tid  = blockIdx.x*256 + threadIdx.x;   // 80 blocks -> 320 tiles
    const int l    = tid & 63, tile = tid >> 6;
    const int ks   = tile & 3, nt = (tile >> 2) & 7;
    const int s    = (tile >> 5) & 1, m = tile >> 6;
    const float* W = (m==0)?wq:(m==1)?wk:(m==2)?wg:(m==3)?wv:wo;
    const float scale = (m==0) ? QSCALE : 1.f;
    const int n  = nt*16 + (l & 15);
    const int kb = ks*32 + (l >> 4)*8;
    unsigned int hw[4];
    #pragma unroll
    for (int jp = 0; jp < 4; ++jp) {
        unsigned short hs[2];
        #pragma unroll
        for (int e = 0; e < 2; ++e) {
            float v = W[(size_t)(kb + jp*2 + e)*C_DIM + n] * scale;
            unsigned short h = f2bf(v);
            if (s) h = f2bf(v - bf2f(h));
            hs[e] = h;
        }
        hw[jp] = (unsigned int)hs[0] | ((unsigned int)hs[1] << 16);
    }
    wfmt_dev[(size_t)m*4096 + (size_t)((s*8 + nt)*4 + ks)*64 + l] =
        make_uint4(hw[0], hw[1], hw[2], hw[3]);
}

// ---------------------------------------------------------------------------
// Kernel 1: LayerNorm + z head + q/k/v/g projections via split-bf16 MFMA.
// (unchanged from round-2 verified version)
// ---------------------------------------------------------------------------
__global__ __launch_bounds__(256, 4) void ln_proj_kernel(
    const float* __restrict__ x,
    const float* __restrict__ lnw, const float* __restrict__ lnb,
    const float* __restrict__ wz,  const float* __restrict__ bz,
    const float* __restrict__ bg,
    float* __restrict__ qo, unsigned short* __restrict__ ko16,
    unsigned int* __restrict__ vto, float* __restrict__ go,
    float* __restrict__ zo)
{
    __shared__ __align__(16) unsigned int xs[4096];   // 16KB: hi, then lo, then vts
    __shared__ __align__(16) uint4 wbuf4[1024];       // 16KB quarter (hi+lo, 2 nt)
    unsigned int* vts = xs;

    const int t    = threadIdx.x;
    const int row0 = blockIdx.x * 64;
    const int w = t >> 6, l = t & 63, n16 = l & 15, quad = l >> 4;

    // ---- prefetch round 0 (wq, quarter 0): 16 tiles, 4 per wave ----
    #pragma unroll
    for (int it = 0; it < 4; ++it) {
        const int tl = w*4 + it;
        const int s = tl >> 3, ntl = (tl >> 2) & 1, ks = tl & 3;
        load_lds16(wfmt_dev + (size_t)((s*8 + ntl)*4 + ks)*64 + l,
                   (char*)wbuf4 + tl*1024);
    }

    // ---- Phase A: LayerNorm + z head; LN results kept in registers ----
    float4 xv[8];
    const int r = t >> 2, qt = t & 3, c0 = qt * 32;
    const int sw = (r & 7) << 2;
    {
        const float* xrow = x + (size_t)(row0 + r)*C_DIM + c0;
        float s = 0.f, ss = 0.f;
        #pragma unroll
        for (int i2 = 0; i2 < 8; i2++) {
            xv[i2] = ((const float4*)xrow)[i2];
            s  += xv[i2].x + xv[i2].y + xv[i2].z + xv[i2].w;
            ss += xv[i2].x*xv[i2].x + xv[i2].y*xv[i2].y
                + xv[i2].z*xv[i2].z + xv[i2].w*xv[i2].w;
        }
        s  += __shfl_xor(s, 1);  s  += __shfl_xor(s, 2);
        ss += __shfl_xor(ss, 1); ss += __shfl_xor(ss, 2);
        const float mean = s * (1.f/128.f);
        const float var  = ss * (1.f/128.f) - mean*mean;
        const float rstd = rsqrtf(var + EPS_F);
        const float4* wz4 = (const float4*)wz;
        float4 zacc = make_float4(0.f,0.f,0.f,0.f);
        #pragma unroll
        for (int i2 = 0; i2 < 8; i2++) {
            float4 w4 = ((const float4*)(lnw + c0))[i2];
            float4 b4 = ((const float4*)(lnb + c0))[i2];
            float4 r4;
            r4.x = (xv[i2].x - mean)*rstd*w4.x + b4.x;
            r4.y = (xv[i2].y - mean)*rstd*w4.y + b4.y;
            r4.z = (xv[i2].z - mean)*rstd*w4.z + b4.z;
            r4.w = (xv[i2].w - mean)*rstd*w4.w + b4.w;
            const float4 za = wz4[c0 + i2*4 + 0];
            const float4 zb_ = wz4[c0 + i2*4 + 1];
            const float4 zc = wz4[c0 + i2*4 + 2];
            const float4 zd = wz4[c0 + i2*4 + 3];
            zacc.x += r4.x*za.x + r4.y*zb_.x + r4.z*zc.x + r4.w*zd.x;
            zacc.y += r4.x*za.y + r4.y*zb_.y + r4.z*zc.y + r4.w*zd.y;
            zacc.z += r4.x*za.z + r4.y*zb_.z + r4.z*zc.z + r4.w*zd.z;
            zacc.w += r4.x*za.w + r4.y*zb_.w + r4.z*zc.w + r4.w*zd.w;
            const int wi = r*64 + qt*16 + i2*2;
            xs[(wi  ) ^ sw] = pk2(r4.x, r4.y);
            xs[(wi+1) ^ sw] = pk2(r4.z, r4.w);
            xv[i2] = r4;
        }
        zacc.x += __shfl_xor(zacc.x, 1); zacc.x += __shfl_xor(zacc.x, 2);
        zacc.y += __shfl_xor(zacc.y, 1); zacc.y += __shfl_xor(zacc.y, 2);
        zacc.z += __shfl_xor(zacc.z, 1); zacc.z += __shfl_xor(zacc.z, 2);
        zacc.w += __shfl_xor(zacc.w, 1); zacc.w += __shfl_xor(zacc.w, 2);
        const float zv = (qt==0)?zacc.x:(qt==1)?zacc.y:(qt==2)?zacc.z:zacc.w;
        zo[(size_t)qt*M_DIM + row0 + r] = zv + bz[qt];
    }
    __syncthreads();

    U4S8 ah[4], al[4];
    const int arow = w*16 + n16;
    #pragma unroll
    for (int ks = 0; ks < 4; ++ks) {
        const int bofs = arow*256 + ((ks*64 + quad*16) ^ ((arow & 7) << 4));
        ah[ks].u = *(const uint4*)((const char*)xs + bofs);
    }
    __syncthreads();

    #pragma unroll
    for (int i2 = 0; i2 < 8; i2++) {
        const float4 r4 = xv[i2];
        const unsigned short h0 = f2bf(r4.x), h1 = f2bf(r4.y),
                             h2 = f2bf(r4.z), h3 = f2bf(r4.w);
        const int wi = r*64 + qt*16 + i2*2;
        xs[(wi  ) ^ sw] = (unsigned int)f2bf(r4.x - bf2f(h0))
                        | ((unsigned int)f2bf(r4.y - bf2f(h1)) << 16);
        xs[(wi+1) ^ sw] = (unsigned int)f2bf(r4.z - bf2f(h2))
                        | ((unsigned int)f2bf(r4.w - bf2f(h3)) << 16);
    }
    __syncthreads();
    #pragma unroll
    for (int ks = 0; ks < 4; ++ks) {
        const int bofs = arow*256 + ((ks*64 + quad*16) ^ ((arow & 7) << 4));
        al[ks].u = *(const uint4*)((const char*)xs + bofs);
    }

    const int i_blk = row0 / I_DIM;
    const int jp0   = (row0 % I_DIM) >> 1;
    const int rw0   = row0 + w*16 + quad*4;

    #pragma unroll
    for (int rd = 0; rd < 16; ++rd) {
        const int mi = rd >> 2, qq = rd & 3;

        f32x4 acc[2];
        #pragma unroll
        for (int ntl = 0; ntl < 2; ++ntl) {
            f32x4 a = {0.f, 0.f, 0.f, 0.f};
            #pragma unroll
            for (int ks = 0; ks < 4; ++ks) {
                U4S8 bh, bl;
                bh.u = wbuf4[(    ntl*4 + ks)*64 + l];
                bl.u = wbuf4[(8 + ntl*4 + ks)*64 + l];
                a = __builtin_amdgcn_mfma_f32_16x16x32_bf16(ah[ks].s, bh.s, a, 0,0,0);
                a = __builtin_amdgcn_mfma_f32_16x16x32_bf16(al[ks].s, bh.s, a, 0,0,0);
                a = __builtin_amdgcn_mfma_f32_16x16x32_bf16(ah[ks].s, bl.s, a, 0,0,0);
            }
            acc[ntl] = a;
        }

        if (mi == 0) {
            #pragma unroll
            for (int ntl = 0; ntl < 2; ++ntl)
                #pragma unroll
                for (int rr = 0; rr < 4; ++rr)
                    qo[(size_t)(rw0 + rr)*C_DIM + qq*32 + ntl*16 + n16] =
                        acc[ntl][rr];
        } else if (mi == 1) {
            #pragma unroll
            for (int ntl = 0; ntl < 2; ++ntl)
                #pragma unroll
                for (int rr = 0; rr < 4; ++rr)
                    ko16[(size_t)(rw0 + rr)*C_DIM + qq*32 + ntl*16 + n16] =
                        f2bf(acc[ntl][rr]);
        } else if (mi == 2) {
            #pragma unroll
            for (int ntl = 0; ntl < 2; ++ntl) {
                const float bgv = bg[qq*32 + ntl*16 + n16];
                #pragma unroll
                for (int rr = 0; rr < 4; ++rr)
                    go[(size_t)(rw0 + rr)*C_DIM + qq*32 + ntl*16 + n16] =
                        1.f/(1.f + __expf(-(acc[ntl][rr] + bgv)));
            }
        } else {
            #pragma unroll
            for (int ntl = 0; ntl < 2; ++ntl)
                #pragma unroll
                for (int pr = 0; pr < 2; ++pr)
                    vts[(ntl*16 + n16)*33 + w*8 + quad*2 + pr] =
                        pk2(acc[ntl][2*pr], acc[ntl][2*pr+1]);
            __syncthreads();
            for (int idx = t; idx < 32*32; idx += 256) {
                const int ch_l = idx >> 5, p = idx & 31;
                vto[((size_t)i_blk*C_DIM + qq*32 + ch_l)*192 + jp0 + p] =
                    vts[ch_l*33 + p];
            }
        }

        __syncthreads();
        if (rd < 15) {
            const int m2 = (rd+1) >> 2, q2 = (rd+1) & 3;
            #pragma unroll
            for (int it = 0; it < 4; ++it) {
                const int tl = w*4 + it;
                const int s = tl >> 3, ntl2 = (tl >> 2) & 1, ks = tl & 3;
                load_lds16(wfmt_dev + (size_t)m2*4096
                           + (size_t)((s*8 + (q2*2 + ntl2))*4 + ks)*64 + l,
                           (char*)wbuf4 + tl*1024);
            }
        }
        __syncthreads();
    }
}

// ---------------------------------------------------------------------------
// Kernel 2: MFMA attention, swapped-operand form.
// QK: S^T = mfma(K,Q) -> lane holds P[q=n16][keys 4*quad..+3] per k6 tile.
//   -> z bias is a row-contiguous float4 load (6 VMEM/chunk vs 96 scalar)
//   -> P->bf16 via v_cvt_pk (same-lane pairs), no shfl-pairing
//   -> PV A-operand exchange = fixed quad permutation: 8 shfl + 4 sel/km
// PV: O^T = mfma(V^T, P) -> lane-local softmax sum + float4 O stores.
// Ks4 XOR-swizzled (slot ^= (key>>1)&3): kills the 8-way bank conflict.
// No P LDS buffer: LDS 51.2 KB -> 3 blocks/CU.
// ---------------------------------------------------------------------------
__global__ __launch_bounds__(256, 3) void attn_mfma_kernel(
    const float* q, const unsigned short* __restrict__ k16,
    const unsigned int* __restrict__ vt32, const float* __restrict__ zb,
    const float* __restrict__ mask, float* o)
{
    __shared__ uint4 Ks4[384*4];              // K rows bf16, swizzled: 24576 B
    __shared__ uint4 VTl[32*49];              // V^T rows bf16, stride 49: 25088 B
    __shared__ __align__(16) float mbl[384];  // 1536 B

    const int ii = blockIdx.x;
    const int h  = blockIdx.y;
    const int t  = threadIdx.x;
    const size_t rbase = (size_t)ii*I_DIM*C_DIM + h*HD_DIM;

    // ---- stage K (swizzled slots) and V^T ----
    for (int idx = t; idx < 1536; idx += 256) {
        const int j = idx >> 2, c4 = idx & 3;
        Ks4[j*4 + (c4 ^ ((j >> 1) & 3))] =
            ((const uint4*)k16)[rbase/8 + (size_t)j*16 + c4];
    }
    for (int idx = t; idx < 1536; idx += 256) {
        const int d = idx / 48, m = idx - d*48;
        VTl[d*49 + m] = ((const uint4*)vt32)[((size_t)ii*C_DIM + h*HD_DIM + d)*48 + m];
    }
    for (int jj = t; jj < 384; jj += 256)
        mbl[jj] = INF_F * (mask[(size_t)ii*I_DIM + jj] - 1.f);
    __syncthreads();

    const int w = t >> 6, l = t & 63;
    const int n16 = l & 15, quad = l >> 4;
    const int slA = n16 + ((quad & 1) << 5);   // source lane: quad' = 2*(quad&1)
    const int slB = slA + 16;                  // quad' + 1
    const bool hi = (quad & 2) != 0;           // selects k6 = 2km+1

    #pragma unroll 1
    for (int qt = 0; qt < 6; qt++) {
        const int qg = w*6 + qt;               // q rows qg*16..+15

        // ---- Q-frag (B-operand): Q[q=n16][d = quad*8..+7] ----
        U4S8 a;
        {
            const float* qrow = q + rbase + (size_t)(qg*16 + n16)*C_DIM + quad*8;
            const float4 f0 = ((const float4*)qrow)[0];
            const float4 f1 = ((const float4*)qrow)[1];
            a.u = make_uint4(cvtpk(f0.x,f0.y), cvtpk(f0.z,f0.w),
                             cvtpk(f1.x,f1.y), cvtpk(f1.z,f1.w));
        }

        f32x4 oacc0 = {0.f,0.f,0.f,0.f}, oacc1 = {0.f,0.f,0.f,0.f};
        float lsum = 0.f;
        const float* zrow = zb + (size_t)h*M_DIM
                          + (size_t)(qg*16 + n16)*I_DIM + quad*4;

        #pragma unroll 1
        for (int c = 0; c < 4; c++) {
            // z bias: row-contiguous float4 per k6 (issued early, used post-MFMA)
            float4 zc4[6];
            #pragma unroll
            for (int k6 = 0; k6 < 6; k6++)
                zc4[k6] = *(const float4*)&zrow[96*c + k6*16];
            // mask bias: broadcast float4 LDS reads
            float4 mb4[6];
            #pragma unroll
            for (int k6 = 0; k6 < 6; k6++)
                mb4[k6] = *(const float4*)&mbl[96*c + k6*16 + quad*4];

            // ---- QK^T swapped: accS[k6][r] = S[q=n16][key=16k6+4quad+r] ----
            f32x4 accS[6];
            #pragma unroll
            for (int k6 = 0; k6 < 6; k6++) {
                const int key = (6*c + k6)*16 + n16;
                U4S8 b;
                b.u = Ks4[key*4 + (quad ^ ((key >> 1) & 3))];
                accS[k6] = __builtin_amdgcn_mfma_f32_16x16x32_bf16(
                    b.s, a.s, (f32x4){0.f,0.f,0.f,0.f}, 0, 0, 0);
            }

            // ---- bias + exp + lane-local sum + pack to bf16 pairs ----
            unsigned int pu[6][2];
            #pragma unroll
            for (int k6 = 0; k6 < 6; k6++) {
                const float e0 = __expf(accS[k6][0] + zc4[k6].x + mb4[k6].x);
                const float e1 = __expf(accS[k6][1] + zc4[k6].y + mb4[k6].y);
                const float e2 = __expf(accS[k6][2] + zc4[k6].z + mb4[k6].z);
                const float e3 = __expf(accS[k6][3] + zc4[k6].w + mb4[k6].w);
                lsum += (e0 + e1) + (e2 + e3);
                pu[k6][0] = cvtpk(e0, e1);
                pu[k6][1] = cvtpk(e2, e3);
            }

            // ---- exchange (fixed quad permutation) + PV ----
            #pragma unroll
            for (int km = 0; km < 3; km++) {
                const unsigned int x0 = __shfl((int)pu[2*km  ][0], slA);
                const unsigned int x1 = __shfl((int)pu[2*km+1][0], slA);
                const unsigned int y0 = __shfl((int)pu[2*km  ][1], slA);
                const unsigned int y1 = __shfl((int)pu[2*km+1][1], slA);
                const unsigned int z0 = __shfl((int)pu[2*km  ][0], slB);
                const unsigned int z1 = __shfl((int)pu[2*km+1][0], slB);
                const unsigned int w0 = __shfl((int)pu[2*km  ][1], slB);
                const unsigned int w1 = __shfl((int)pu[2*km+1][1], slB);
                U4S8 pa;
                pa.u = make_uint4(hi?x1:x0, hi?y1:y0, hi?z1:z0, hi?w1:w0);
                U4S8 vb0, vb1;
                vb0.u = VTl[(n16     )*49 + quad + 4*km + 12*c];
                vb1.u = VTl[(16 + n16)*49 + quad + 4*km + 12*c];
                oacc0 = __builtin_amdgcn_mfma_f32_16x16x32_bf16(vb0.s, pa.s, oacc0, 0,0,0);
                oacc1 = __builtin_amdgcn_mfma_f32_16x16x32_bf16(vb1.s, pa.s, oacc1, 0,0,0);
            }
        }

        // ---- normalize + store: lane holds O[q=n16][d=quad*4+r (+16)] ----
        float s_ = lsum;
        s_ += __shfl_xor(s_, 16);
        s_ += __shfl_xor(s_, 32);
        const float rcp = 1.f / s_;
        const size_t orow = rbase + (size_t)(qg*16 + n16)*C_DIM;
        float4 o0 = make_float4(oacc0[0]*rcp, oacc0[1]*rcp,
                                oacc0[2]*rcp, oacc0[3]*rcp);
        float4 o1 = make_float4(oacc1[0]*rcp, oacc1[1]*rcp,
                                oacc1[2]*rcp, oacc1[3]*rcp);
        *(float4*)&o[orow + quad*4]      = o0;
        *(float4*)&o[orow + 16 + quad*4] = o1;
    }
}

// ---------------------------------------------------------------------------
// Kernel 3: out = (o * g) @ wo + bo (unchanged from round-2 verified version).
// ---------------------------------------------------------------------------
__global__ __launch_bounds__(256, 4) void out_proj_kernel(
    const float* __restrict__ o, const float* g,
    const float* __restrict__ bo, float* out)
{
    __shared__ __align__(16) unsigned int xs[4096];
    __shared__ __align__(16) uint4 wbuf4[1024];
    const int t    = threadIdx.x;
    const int row0 = blockIdx.x * 64;
    const int w = t >> 6, l = t & 63, n16 = l & 15, quad = l >> 4;

    #pragma unroll
    for (int it = 0; it < 4; ++it) {
        const int tl = w*4 + it;
        const int s = tl >> 3, ntl = (tl >> 2) & 1, ks = tl & 3;
        load_lds16(wfmt_dev + (size_t)4*4096 + (size_t)((s*8 + ntl)*4 + ks)*64 + l,
                   (char*)wbuf4 + tl*1024);
    }

    float4 pv[8];
    const int r = t >> 2, qt = t & 3, c0 = qt * 32;
    const int sw = (r & 7) << 2;
    {
        const float4* orow = (const float4*)(o + (size_t)(row0 + r)*C_DIM + c0);
        const float4* grow = (const float4*)(g + (size_t)(row0 + r)*C_DIM + c0);
        #pragma unroll
        for (int i2 = 0; i2 < 8; i2++) {
            const float4 a = orow[i2];
            const float4 b = grow[i2];
            float4 p;
            p.x = a.x*b.x; p.y = a.y*b.y; p.z = a.z*b.z; p.w = a.w*b.w;
            const int wi = r*64 + qt*16 + i2*2;
            xs[(wi  ) ^ sw] = pk2(p.x, p.y);
            xs[(wi+1) ^ sw] = pk2(p.z, p.w);
            pv[i2] = p;
        }
    }
    __syncthreads();

    U4S8 ah[4], al[4];
    const int arow = w*16 + n16;
    #pragma unroll
    for (int ks = 0; ks < 4; ++ks) {
        const int bofs = arow*256 + ((ks*64 + quad*16) ^ ((arow & 7) << 4));
        ah[ks].u = *(const uint4*)((const char*)xs + bofs);
    }
    __syncthreads();
    #pragma unroll
    for (int i2 = 0; i2 < 8; i2++) {
        const float4 p = pv[i2];
        const unsigned short h0 = f2bf(p.x), h1 = f2bf(p.y),
                             h2 = f2bf(p.z), h3 = f2bf(p.w);
        const int wi = r*64 + qt*16 + i2*2;
        xs[(wi  ) ^ sw] = (unsigned int)f2bf(p.x - bf2f(h0))
                        | ((unsigned int)f2bf(p.y - bf2f(h1)) << 16);
        xs[(wi+1) ^ sw] = (unsigned int)f2bf(p.z - bf2f(h2))
                        | ((unsigned int)f2bf(p.w - bf2f(h3)) << 16);
    }
    __syncthreads();
    #pragma unroll
    for (int ks = 0; ks < 4; ++ks) {
        const int bofs = arow*256 + ((ks*64 + quad*16) ^ ((arow & 7) << 4));
        al[ks].u = *(const uint4*)((const char*)xs + bofs);
    }

    const int rw0 = row0 + w*16 + quad*4;
    #pragma unroll
    for (int qq = 0; qq < 4; ++qq) {
        f32x4 acc[2];
        #pragma unroll
        for (int ntl = 0; ntl < 2; ++ntl) {
            f32x4 a = {0.f, 0.f, 0.f, 0.f};
            #pragma unroll
            for (int ks = 0; ks < 4; ++ks) {
                U4S8 bh, bl;
                bh.u = wbuf4[(    ntl*4 + ks)*64 + l];
                bl.u = wbuf4[(8 + ntl*4 + ks)*64 + l];
                a = __builtin_amdgcn_mfma_f32_16x16x32_bf16(ah[ks].s, bh.s, a, 0,0,0);
                a = __builtin_amdgcn_mfma_f32_16x16x32_bf16(al[ks].s, bh.s, a, 0,0,0);
                a = __builtin_amdgcn_mfma_f32_16x16x32_bf16(ah[ks].s, bl.s, a, 0,0,0);
            }
            acc[ntl] = a;
        }
        #pragma unroll
        for (int ntl = 0; ntl < 2; ++ntl) {
            const int n = qq*32 + ntl*16 + n16;
            const float bov = bo[n];
            #pragma unroll
            for (int rr = 0; rr < 4; ++rr)
                out[(size_t)(rw0 + rr)*C_DIM + n] = acc[ntl][rr] + bov;
        }
        __syncthreads();
        if (qq < 3) {
            const int q2 = qq + 1;
            #pragma unroll
            for (int it = 0; it < 4; ++it) {
                const int tl = w*4 + it;
                const int s = tl >> 3, ntl2 = (tl >> 2) & 1, ks = tl & 3;
                load_lds16(wfmt_dev + (size_t)4*4096
                           + (size_t)((s*8 + (q2*2 + ntl2))*4 + ks)*64 + l,
                           (char*)wbuf4 + tl*1024);
            }
        }
        __syncthreads();
    }
}

extern "C" void kernel_launch(void* const* d_in, const int* in_sizes, int n_in,
                              void* d_out, int out_size, void* d_ws, size_t ws_size,
                              hipStream_t stream)
{
    (void)in_sizes; (void)n_in; (void)out_size; (void)ws_size;
    const float* x    = (const float*)d_in[0];
    const float* mask = (const float*)d_in[1];
    const float* lnw  = (const float*)d_in[2];
    const float* lnb  = (const float*)d_in[3];
    const float* wz   = (const float*)d_in[4];
    const float* bz   = (const float*)d_in[5];
    const float* wq   = (const float*)d_in[6];
    const float* wk   = (const float*)d_in[7];
    const float* wv   = (const float*)d_in[8];
    const float* wg   = (const float*)d_in[9];
    const float* bg   = (const float*)d_in[10];
    const float* wo   = (const float*)d_in[11];
    const float* bo   = (const float*)d_in[12];

    // ws layout (153.4 MB, unchanged):
    //   qb   fp32 M*128  (q; o overwrites it in attention)
    //   zbuf fp32 4*M
    //   kb16 bf16 M*128 row-major
    //   vt32 bf16 M*128 transposed [i][c][j], packed uint pairs along j
    float* ws = (float*)d_ws;
    float* qb   = ws;
    float* zbuf = qb + (size_t)M_DIM*C_DIM;
    unsigned short* kb16 = (unsigned short*)(zbuf + (size_t)H_NUM*M_DIM);
    unsigned int*   vt32 = (unsigned int*)(kb16 + (size_t)M_DIM*C_DIM);
    float* gbuf = (float*)d_out;     // g parked in d_out, consumed by kernel 3

    wprep_kernel<<<80, 256, 0, stream>>>(wq, wk, wg, wv, wo);
    ln_proj_kernel<<<M_DIM/64, 256, 0, stream>>>(
        x, lnw, lnb, wz, bz, bg, qb, kb16, vt32, gbuf, zbuf);
    attn_mfma_kernel<<<dim3(I_DIM, H_NUM), 256, 0, stream>>>(
        qb, kb16, vt32, zbuf, mask, qb /* o over q */);
    out_proj_kernel<<<M_DIM/64, 256, 0, stream>>>(
        qb, gbuf, bo, (float*)d_out);
}